// Round 1
// baseline (1072.670 us; speedup 1.0000x reference)
//
#include <hip/hip_runtime.h>
#include <hip/hip_bf16.h>
#include <math.h>

#define NA 50000
#define NE 800000
#define NB 128   // atom basis == filters
#define NG 64

__device__ __forceinline__ float ssp(float x) {
    // softplus(x) - log(2), numerically stable
    float sp = (x > 15.0f) ? x : log1pf(__expf(x));
    return sp - 0.69314718f;
}

// C[M,128] = act(A[M,128] @ W[128,128] + b)
// block = 256 threads (2 halves x 128 f). Each half computes 4 rows at a time.
template<int ACT>
__global__ __launch_bounds__(256) void gemm128(const float* __restrict__ A,
                                               const float* __restrict__ W,
                                               const float* __restrict__ b,
                                               float* __restrict__ C, int M) {
    __shared__ float sW[128 * 128];   // 64 KB
    __shared__ float sRow[8][128];    // 4 KB
    const int tid  = threadIdx.x;
    const int f    = tid & 127;
    const int half = tid >> 7;        // 0 or 1
    for (int i = tid; i < 128 * 128; i += 256) sW[i] = W[i];
    const float bias = b ? b[f] : 0.0f;
    __syncthreads();

    for (int base = blockIdx.x * 64; base < M; base += gridDim.x * 64) {
        for (int c = 0; c < 64; c += 8) {
            __syncthreads();
            // stage 8 rows cooperatively
            #pragma unroll
            for (int j = 0; j < 4; ++j) {
                int idx = tid + j * 256;      // 0..1023
                int rr  = idx >> 7;           // 0..7
                int col = idx & 127;
                int row = base + c + rr;
                sRow[rr][col] = (row < M) ? A[(size_t)row * 128 + col] : 0.0f;
            }
            __syncthreads();

            float acc0 = bias, acc1 = bias, acc2 = bias, acc3 = bias;
            const int r0 = half * 4;
            for (int k = 0; k < 128; k += 4) {
                float4 a0 = *(const float4*)&sRow[r0 + 0][k];
                float4 a1 = *(const float4*)&sRow[r0 + 1][k];
                float4 a2 = *(const float4*)&sRow[r0 + 2][k];
                float4 a3 = *(const float4*)&sRow[r0 + 3][k];
                float w;
                w = sW[(k + 0) * 128 + f];
                acc0 = fmaf(a0.x, w, acc0); acc1 = fmaf(a1.x, w, acc1);
                acc2 = fmaf(a2.x, w, acc2); acc3 = fmaf(a3.x, w, acc3);
                w = sW[(k + 1) * 128 + f];
                acc0 = fmaf(a0.y, w, acc0); acc1 = fmaf(a1.y, w, acc1);
                acc2 = fmaf(a2.y, w, acc2); acc3 = fmaf(a3.y, w, acc3);
                w = sW[(k + 2) * 128 + f];
                acc0 = fmaf(a0.z, w, acc0); acc1 = fmaf(a1.z, w, acc1);
                acc2 = fmaf(a2.z, w, acc2); acc3 = fmaf(a3.z, w, acc3);
                w = sW[(k + 3) * 128 + f];
                acc0 = fmaf(a0.w, w, acc0); acc1 = fmaf(a1.w, w, acc1);
                acc2 = fmaf(a2.w, w, acc2); acc3 = fmaf(a3.w, w, acc3);
            }
            float acc[4] = {acc0, acc1, acc2, acc3};
            #pragma unroll
            for (int j = 0; j < 4; ++j) {
                int row = base + c + r0 + j;
                if (row < M) {
                    float v = acc[j];
                    if (ACT == 1) v = ssp(v);
                    C[(size_t)row * 128 + f] = v;
                }
            }
        }
    }
}

// Fused: gaussian smearing -> filter GEMM (g @ Wf2 + bf2) -> gather rf[src]
// -> elementwise modulate -> atomic scatter-add to seg[dst].
// One wave (64 lanes) per edge; lane owns filters f=lane and f=lane+64.
__global__ __launch_bounds__(256) void edge_kernel(const float* __restrict__ e,
                                                   const int* __restrict__ a,
                                                   const float* __restrict__ Wf2,
                                                   const float* __restrict__ bf2,
                                                   const float* __restrict__ rf,
                                                   float* __restrict__ seg) {
    __shared__ float sW[NG * 128];   // 32 KB
    const int tid = threadIdx.x;
    for (int i = tid; i < NG * 128; i += 256) sW[i] = Wf2[i];
    __syncthreads();

    const int lane = tid & 63;
    const int wave = tid >> 6;
    const float coeff = -0.5f * (63.0f / 5.0f) * (63.0f / 5.0f);   // -0.5/width^2
    const float off   = (5.0f / 63.0f) * (float)lane;              // linspace(0,5,64)[lane]
    const float b0 = bf2[lane];
    const float b1 = bf2[lane + 64];

    for (int edge = blockIdx.x * 4 + wave; edge < NE; edge += gridDim.x * 4) {
        float ev  = e[edge];
        int   dst = a[2 * edge];
        int   src = a[2 * edge + 1];
        float d = ev - off;
        float g = __expf(coeff * d * d);   // this lane's gaussian (k = lane)

        float acc0 = b0, acc1 = b1;
        #pragma unroll
        for (int k = 0; k < 64; ++k) {
            float gk = __shfl(g, k, 64);
            acc0 = fmaf(gk, sW[k * 128 + lane], acc0);
            acc1 = fmaf(gk, sW[k * 128 + 64 + lane], acc1);
        }
        float r0 = rf[(size_t)src * 128 + lane];
        float r1 = rf[(size_t)src * 128 + 64 + lane];
        atomicAdd(&seg[(size_t)dst * 128 + lane],      r0 * acc0);
        atomicAdd(&seg[(size_t)dst * 128 + 64 + lane], r1 * acc1);
    }
}

extern "C" void kernel_launch(void* const* d_in, const int* in_sizes, int n_in,
                              void* d_out, int out_size, void* d_ws, size_t ws_size,
                              hipStream_t stream) {
    const float* r   = (const float*)d_in[0];
    const float* e   = (const float*)d_in[1];
    const float* Wf2 = (const float*)d_in[2];
    const float* bf2 = (const float*)d_in[3];
    const float* Wa  = (const float*)d_in[4];
    const float* W1  = (const float*)d_in[5];
    const float* b1  = (const float*)d_in[6];
    const float* W2  = (const float*)d_in[7];
    const float* b2  = (const float*)d_in[8];
    const int*   a   = (const int*)d_in[9];

    float* out  = (float*)d_out;
    float* buf0 = (float*)d_ws;   // rf, later reused for y1 (25.6 MB)
    float* seg  = out;            // reuse d_out as the segment-sum buffer

    // rf = r @ Wa (no bias)
    gemm128<0><<<782, 256, 0, stream>>>(r, Wa, nullptr, buf0, NA);
    // zero the segment-sum accumulator (we own d_out's contents)
    hipMemsetAsync(seg, 0, (size_t)NA * 128 * sizeof(float), stream);
    // fused edge pipeline
    edge_kernel<<<3125, 256, 0, stream>>>(e, a, Wf2, bf2, buf0, seg);
    // y1 = ssp(seg @ W1 + b1)  (seg == d_out read, buf0 written)
    gemm128<1><<<782, 256, 0, stream>>>(seg, W1, b1, buf0, NA);
    // out = y1 @ W2 + b2
    gemm128<0><<<782, 256, 0, stream>>>(buf0, W2, b2, out, NA);
}

// Round 2
// 467.072 us; speedup vs baseline: 2.2966x; 2.2966x over previous
//
#include <hip/hip_runtime.h>
#include <hip/hip_bf16.h>
#include <math.h>

#define NA 50000
#define NE 800000
#define NG 64

typedef float f32x4 __attribute__((ext_vector_type(4)));
typedef __bf16 bf16x8 __attribute__((ext_vector_type(8)));

__device__ __forceinline__ float ssp(float x) {
    float sp = (x > 15.0f) ? x : log1pf(__expf(x));
    return sp - 0.69314718f;
}

// ---------------------------------------------------------------------------
// Edge pipeline: gaussian smearing -> (g @ Wf2 + bf2) via MFMA (hi/lo split)
// -> gather rf[src] -> modulate -> atomic scatter-add into seg[dst].
// Block = 256 thr (4 waves); each block owns 128 edges. Wave w owns edges
// [w*32, w*32+32) as 2 M-tiles of 16. N = 128 filters = 8 N-tiles. K = 64.
// ---------------------------------------------------------------------------
__global__ __launch_bounds__(256) void edge_mfma(const float* __restrict__ e,
                                                 const int* __restrict__ a,
                                                 const float* __restrict__ Wf2,
                                                 const float* __restrict__ bf2,
                                                 const float* __restrict__ rf,
                                                 float* __restrict__ seg) {
    __shared__ __bf16 sWhi[128 * 64];   // Wf2^T hi, [n][k] with k8 XOR-swizzle
    __shared__ __bf16 sWlo[128 * 64];   // Wf2^T lo
    __shared__ float  se[128];
    __shared__ int    sdst[128], ssrc[128];

    const int tid = threadIdx.x;

    // Stage Wf2 [64][128] fp32 -> transposed hi/lo bf16, swizzled k-blocks.
    for (int i = tid; i < 64 * 128; i += 256) {
        int k = i >> 7, n = i & 127;
        float v = Wf2[i];
        __bf16 h = (__bf16)v;
        __bf16 l = (__bf16)(v - (float)h);
        int addr = n * 64 + (((k >> 3) ^ (n & 7)) << 3) + (k & 7);
        sWhi[addr] = h;
        sWlo[addr] = l;
    }
    const int base = blockIdx.x * 128;   // 800000 / 128 = 6250 exact, no tail
    if (tid < 128) {
        se[tid]   = e[base + tid];
        sdst[tid] = a[2 * (base + tid)];
        ssrc[tid] = a[2 * (base + tid) + 1];
    }
    __syncthreads();

    const int lane = tid & 63, w = tid >> 6;
    const int lrow = lane & 15, lgrp = lane >> 4;

    // bias (added in fp32 during scatter)
    float bv[8];
    #pragma unroll
    for (int nt = 0; nt < 8; ++nt) bv[nt] = bf2[nt * 16 + lrow];

    // A fragments: g = exp(coeff*(e-off_k)^2), computed analytically, split hi/lo.
    const float coeff = -0.5f * (63.0f / 5.0f) * (63.0f / 5.0f);
    bf16x8 ah[2][2], al[2][2];
    #pragma unroll
    for (int mt = 0; mt < 2; ++mt) {
        float ev = se[w * 32 + mt * 16 + lrow];
        #pragma unroll
        for (int ks = 0; ks < 2; ++ks) {
            #pragma unroll
            for (int j = 0; j < 8; ++j) {
                int k = ks * 32 + lgrp * 8 + j;
                float d = ev - (5.0f / 63.0f) * (float)k;
                float g = __expf(coeff * d * d);
                __bf16 h = (__bf16)g;
                ah[mt][ks][j] = h;
                al[mt][ks][j] = (__bf16)(g - (float)h);
            }
        }
    }

    f32x4 acc[2][8];
    #pragma unroll
    for (int mt = 0; mt < 2; ++mt)
        #pragma unroll
        for (int nt = 0; nt < 8; ++nt)
            acc[mt][nt] = (f32x4){0.f, 0.f, 0.f, 0.f};

    #pragma unroll
    for (int ks = 0; ks < 2; ++ks) {
        #pragma unroll
        for (int nt = 0; nt < 8; ++nt) {
            int n = nt * 16 + lrow;
            int k8 = ks * 4 + lgrp;
            int addr = n * 64 + ((k8 ^ (n & 7)) << 3);
            bf16x8 bh = *(const bf16x8*)&sWhi[addr];
            bf16x8 bl = *(const bf16x8*)&sWlo[addr];
            #pragma unroll
            for (int mt = 0; mt < 2; ++mt) {
                acc[mt][nt] = __builtin_amdgcn_mfma_f32_16x16x32_bf16(ah[mt][ks], bh, acc[mt][nt], 0, 0, 0);
                acc[mt][nt] = __builtin_amdgcn_mfma_f32_16x16x32_bf16(ah[mt][ks], bl, acc[mt][nt], 0, 0, 0);
                acc[mt][nt] = __builtin_amdgcn_mfma_f32_16x16x32_bf16(al[mt][ks], bh, acc[mt][nt], 0, 0, 0);
            }
        }
    }

    // Scatter: C layout col = lane&15, row = (lane>>4)*4 + reg  [m89]
    #pragma unroll
    for (int mt = 0; mt < 2; ++mt) {
        #pragma unroll
        for (int r = 0; r < 4; ++r) {
            int el  = w * 32 + mt * 16 + lgrp * 4 + r;
            int dst = sdst[el];
            int src = ssrc[el];
            const float* rfp = rf + (size_t)src * 128 + lrow;
            float*       sp  = seg + (size_t)dst * 128 + lrow;
            #pragma unroll
            for (int nt = 0; nt < 8; ++nt) {
                float wv = acc[mt][nt][r] + bv[nt];
                float y  = rfp[nt * 16] * wv;
                atomicAdd(&sp[nt * 16], y);
            }
        }
    }
}

// ---------------------------------------------------------------------------
// Dense GEMM: C[M,128] = act(A[M,128] @ W[128,128] + b), hi/lo split MFMA.
// Block 256 (4 waves); wave w owns rows [blk*64 + w*16, +16). K = 128.
// ---------------------------------------------------------------------------
template<int ACT, int BIAS>
__global__ __launch_bounds__(256) void mfma_gemm(const float* __restrict__ A,
                                                 const float* __restrict__ W,
                                                 const float* __restrict__ b,
                                                 float* __restrict__ C, int M) {
    __shared__ __bf16 sWhi[128 * 128];  // W^T hi, [n][k], k8 XOR-swizzled
    __shared__ __bf16 sWlo[128 * 128];

    const int tid = threadIdx.x;
    for (int i = tid; i < 128 * 128; i += 256) {
        int k = i >> 7, n = i & 127;
        float v = W[i];
        __bf16 h = (__bf16)v;
        __bf16 l = (__bf16)(v - (float)h);
        int addr = n * 128 + (((k >> 3) ^ (n & 15)) << 3) + (k & 7);
        sWhi[addr] = h;
        sWlo[addr] = l;
    }
    __syncthreads();

    const int lane = tid & 63, w = tid >> 6;
    const int lrow = lane & 15, lgrp = lane >> 4;

    float bv[8];
    #pragma unroll
    for (int nt = 0; nt < 8; ++nt) bv[nt] = BIAS ? b[nt * 16 + lrow] : 0.0f;

    const int row  = blockIdx.x * 64 + w * 16 + lrow;
    const int rowc = row < M ? row : M - 1;           // clamp; result discarded

    f32x4 acc[8];
    #pragma unroll
    for (int nt = 0; nt < 8; ++nt) acc[nt] = (f32x4){0.f, 0.f, 0.f, 0.f};

    #pragma unroll
    for (int ks = 0; ks < 4; ++ks) {
        int k0 = ks * 32 + lgrp * 8;
        float4 f0 = *(const float4*)&A[(size_t)rowc * 128 + k0];
        float4 f1 = *(const float4*)&A[(size_t)rowc * 128 + k0 + 4];
        float av[8] = {f0.x, f0.y, f0.z, f0.w, f1.x, f1.y, f1.z, f1.w};
        bf16x8 ah, al;
        #pragma unroll
        for (int j = 0; j < 8; ++j) {
            __bf16 h = (__bf16)av[j];
            ah[j] = h;
            al[j] = (__bf16)(av[j] - (float)h);
        }
        #pragma unroll
        for (int nt = 0; nt < 8; ++nt) {
            int n = nt * 16 + lrow;
            int k8 = ks * 4 + lgrp;     // 0..15
            int addr = n * 128 + ((k8 ^ (n & 15)) << 3);
            bf16x8 bh = *(const bf16x8*)&sWhi[addr];
            bf16x8 bl = *(const bf16x8*)&sWlo[addr];
            acc[nt] = __builtin_amdgcn_mfma_f32_16x16x32_bf16(ah, bh, acc[nt], 0, 0, 0);
            acc[nt] = __builtin_amdgcn_mfma_f32_16x16x32_bf16(ah, bl, acc[nt], 0, 0, 0);
            acc[nt] = __builtin_amdgcn_mfma_f32_16x16x32_bf16(al, bh, acc[nt], 0, 0, 0);
        }
    }

    const int orow = blockIdx.x * 64 + w * 16 + lgrp * 4;
    #pragma unroll
    for (int r = 0; r < 4; ++r) {
        if (orow + r < M) {
            #pragma unroll
            for (int nt = 0; nt < 8; ++nt) {
                float v = acc[nt][r] + bv[nt];
                if (ACT) v = ssp(v);
                C[(size_t)(orow + r) * 128 + nt * 16 + lrow] = v;
            }
        }
    }
}

extern "C" void kernel_launch(void* const* d_in, const int* in_sizes, int n_in,
                              void* d_out, int out_size, void* d_ws, size_t ws_size,
                              hipStream_t stream) {
    const float* r   = (const float*)d_in[0];
    const float* e   = (const float*)d_in[1];
    const float* Wf2 = (const float*)d_in[2];
    const float* bf2 = (const float*)d_in[3];
    const float* Wa  = (const float*)d_in[4];
    const float* W1  = (const float*)d_in[5];
    const float* b1  = (const float*)d_in[6];
    const float* W2  = (const float*)d_in[7];
    const float* b2  = (const float*)d_in[8];
    const int*   a   = (const int*)d_in[9];

    float* out  = (float*)d_out;
    float* buf0 = (float*)d_ws;    // rf, later y1 (25.6 MB)
    float* seg  = out;             // d_out doubles as segment-sum accumulator

    const int gblocks = (NA + 63) / 64;   // 782

    // rf = r @ Wa
    mfma_gemm<0, 0><<<gblocks, 256, 0, stream>>>(r, Wa, nullptr, buf0, NA);
    // zero segment accumulator
    hipMemsetAsync(seg, 0, (size_t)NA * 128 * sizeof(float), stream);
    // fused edge pipeline
    edge_mfma<<<NE / 128, 256, 0, stream>>>(e, a, Wf2, bf2, buf0, seg);
    // y1 = ssp(seg @ W1 + b1)
    mfma_gemm<1, 1><<<gblocks, 256, 0, stream>>>(seg, W1, b1, buf0, NA);
    // out = y1 @ W2 + b2
    mfma_gemm<0, 1><<<gblocks, 256, 0, stream>>>(buf0, W2, b2, out, NA);
}